// Round 13
// baseline (267.444 us; speedup 1.0000x reference)
//
#include <hip/hip_runtime.h>

// ClassicPINN forward, round 13.
// Round-12 confirmed: k-pair f32x2 packing + scalar (s_load) weights, no LDS
// = 146us best (SGPR=112 scalarization fired, conflicts 0, VALUBusy 80%).
// Remaining 2x gap vs ~73us issue floor = SMEM weight stream: ~2084 s_loads
// per wave against a 112-SGPR budget -> batch loads + lgkmcnt waits, each
// batch amortized over just 64 points of FMA.
// Fix: P=2 points/thread. Same weight SGPR pair feeds 2 back-to-back
// v_pk_fma -> per-point SMEM instructions and batch-head waits HALVE.
// Vector side has zero memory ops, so fatter state (~140 VGPR, 3.5 waves/
// SIMD) is fine: latency is covered by doubled per-batch compute.
// Per-point arithmetic identical to round 12 -> absmax unchanged.

#define NPTS 1048576
#define P 2  // points per thread

typedef float f32x2 __attribute__((ext_vector_type(2)));

struct PinnParams {
    const float* W[15];
    const float* B[15];
};

__device__ __forceinline__ float fast_tanh(float x) {
    // tanh(x) = 1 - 2/(exp(2x)+1); exp(2x)=exp2(x*2*log2e). Clamp +-9.5
    // (v_med3_f32) saturates to 1.0f exactly like tanhf. Same as rounds 1-12.
    x = __builtin_amdgcn_fmed3f(x, -9.5f, 9.5f);
    float e = __builtin_amdgcn_exp2f(x * 2.8853900817779268f);
    return 1.0f - 2.0f * __builtin_amdgcn_rcpf(e + 1.0f);
}

// Generic layer, k-pair packed, weights from GLOBAL (uniform -> s_load),
// P points per thread. h2/o2: [P][16] f32x2 arrays, static indices only.
// acc.x accumulates bias+even-k, acc.y odd-k; horizontal add at the end.
template <int IN, int OUT, bool TANH>
__device__ __forceinline__ void layerK(const float* __restrict__ W,
                                       const float* __restrict__ B,
                                       const f32x2 (*h2)[16], f32x2 (*o2)[16]) {
    static_assert(IN % 2 == 0 && OUT % 2 == 0, "");
#pragma unroll
    for (int j = 0; j < OUT; ++j) {
        const float bj = B[j];  // uniform s_load
        f32x2 acc[P];
#pragma unroll
        for (int p = 0; p < P; ++p) acc[p] = f32x2{bj, 0.0f};
#pragma unroll
        for (int k2 = 0; k2 < IN / 2; ++k2) {
            // uniform row-major pair -> SGPR pair, shared by P pk_fmas
            const f32x2 w = *reinterpret_cast<const f32x2*>(W + j * IN + 2 * k2);
#pragma unroll
            for (int p = 0; p < P; ++p)
                acc[p] = __builtin_elementwise_fma(w, h2[p][k2], acc[p]);
        }
#pragma unroll
        for (int p = 0; p < P; ++p) {
            const float s = acc[p].x + acc[p].y;
            const float r = TANH ? fast_tanh(s) : s;
            if (j & 1) o2[p][j >> 1].y = r; else o2[p][j >> 1].x = r;
        }
    }
}

// First layer: 3 -> 8 (IN=3 scalar weights, 24 of them).
__device__ __forceinline__ void layer0(const float* __restrict__ W,
                                       const float* __restrict__ B,
                                       const float (*h0)[3], f32x2 (*o2)[16]) {
#pragma unroll
    for (int j = 0; j < 8; ++j) {
        const float w0 = W[3 * j + 0], w1 = W[3 * j + 1], w2 = W[3 * j + 2];
        const float bj = B[j];
#pragma unroll
        for (int p = 0; p < P; ++p) {
            float s = fmaf(w0, h0[p][0], bj);
            s = fmaf(w1, h0[p][1], s);
            s = fmaf(w2, h0[p][2], s);
            const float r = fast_tanh(s);
            if (j & 1) o2[p][j >> 1].y = r; else o2[p][j >> 1].x = r;
        }
    }
}

// Last layer: 16 -> 3, no tanh.
__device__ __forceinline__ void layer14(const float* __restrict__ W,
                                        const float* __restrict__ B,
                                        const f32x2 (*h2)[16], float (*o)[3]) {
#pragma unroll
    for (int j = 0; j < 3; ++j) {
        const float bj = B[j];
        f32x2 acc[P];
#pragma unroll
        for (int p = 0; p < P; ++p) acc[p] = f32x2{bj, 0.0f};
#pragma unroll
        for (int k2 = 0; k2 < 8; ++k2) {
            const f32x2 w = *reinterpret_cast<const f32x2*>(W + j * 16 + 2 * k2);
#pragma unroll
            for (int p = 0; p < P; ++p)
                acc[p] = __builtin_elementwise_fma(w, h2[p][k2], acc[p]);
        }
#pragma unroll
        for (int p = 0; p < P; ++p) o[p][j] = acc[p].x + acc[p].y;
    }
}

__global__ __launch_bounds__(256, 3) void pinn_fwd(const float* __restrict__ coords,
                                                   PinnParams prm,
                                                   float* __restrict__ out) {
    const int t = blockIdx.x * 256 + threadIdx.x;
    const int i0 = t * P;

    // coords for 2 points: 6 floats = 3 aligned f32x2 loads
    const f32x2* cp = reinterpret_cast<const f32x2*>(coords + 3 * i0);
    const f32x2 q0 = cp[0], q1 = cp[1], q2 = cp[2];  // {x0,y0}{z0,x1}{y1,z1}
    float h0[P][3];
    h0[0][0] = q0.x; h0[0][1] = q0.y; h0[0][2] = q1.x;
    h0[1][0] = q1.y; h0[1][1] = q2.x; h0[1][2] = q2.y;

    f32x2 a2[P][16], c2[P][16];  // ping-pong activations, static indices only

    layer0(prm.W[0], prm.B[0], h0, a2);                 // 3 -> 8
    layerK<8, 8, true>(prm.W[1], prm.B[1], a2, c2);
    layerK<8, 8, true>(prm.W[2], prm.B[2], c2, a2);
    layerK<8, 8, true>(prm.W[3], prm.B[3], a2, c2);
    layerK<8, 8, true>(prm.W[4], prm.B[4], c2, a2);
    layerK<8, 8, true>(prm.W[5], prm.B[5], a2, c2);
    layerK<8, 8, true>(prm.W[6], prm.B[6], c2, a2);
    layerK<8, 16, true>(prm.W[7], prm.B[7], a2, c2);    // 8 -> 16
    layerK<16, 16, true>(prm.W[8], prm.B[8], c2, a2);
    layerK<16, 16, true>(prm.W[9], prm.B[9], a2, c2);
    layerK<16, 32, true>(prm.W[10], prm.B[10], c2, a2); // 16 -> 32
    layerK<32, 32, true>(prm.W[11], prm.B[11], a2, c2);
    layerK<32, 32, true>(prm.W[12], prm.B[12], c2, a2);
    layerK<32, 16, true>(prm.W[13], prm.B[13], a2, c2); // 32 -> 16
    float o[P][3];
    layer14(prm.W[14], prm.B[14], c2, o);               // 16 -> 3, no tanh

    // outputs concatenated (h[:,0], h[:,1], h[:,2]); adjacent pair -> f32x2
    *reinterpret_cast<f32x2*>(out + i0) = f32x2{o[0][0], o[1][0]};
    *reinterpret_cast<f32x2*>(out + NPTS + i0) = f32x2{o[0][1], o[1][1]};
    *reinterpret_cast<f32x2*>(out + 2 * NPTS + i0) = f32x2{o[0][2], o[1][2]};
}

extern "C" void kernel_launch(void* const* d_in, const int* in_sizes, int n_in,
                              void* d_out, int out_size, void* d_ws, size_t ws_size,
                              hipStream_t stream) {
    const float* coords = (const float*)d_in[0];
    PinnParams prm;
    for (int l = 0; l < 15; ++l) {
        prm.W[l] = (const float*)d_in[1 + 2 * l];
        prm.B[l] = (const float*)d_in[2 + 2 * l];
    }
    pinn_fwd<<<NPTS / (256 * P), 256, 0, stream>>>(coords, prm, (float*)d_out);
}